// Round 4
// baseline (192.205 us; speedup 1.0000x reference)
//
#include <hip/hip_runtime.h>
#include <math.h>

#define BATCH 16
#define CH 256
#define HW 56
#define NPIX (HW*HW)          // 3136

typedef float f32x2 __attribute__((ext_vector_type(2)));

// ---- shared device helper: compute 4x4 tile of x_fuse = relu6(bn1(dw1(x))) * bn2(dw2(x))
// Dual 3x3 convs packed as f32x2 (v_pk_fma_f32 path); scalarizes harmlessly if unsupported.
// Tile at rows 4ty..4ty+3, cols 4tx..4tx+3 (ty,tx in 0..13).
__device__ __forceinline__ void fuse_tile(
    const float* __restrict__ plane, int ty, int tx,
    const f32x2 w12[9], f32x2 sc12, f32x2 be12,
    float res[4][4])
{
    const int oy = 4 * ty;
    f32x2 y12a[4][4];
    #pragma unroll
    for (int a = 0; a < 4; a++)
        #pragma unroll
        for (int e = 0; e < 4; e++) y12a[a][e] = (f32x2){0.f, 0.f};

    #pragma unroll
    for (int iy = 0; iy < 6; iy++) {         // input rows oy-1 .. oy+4
        const int r    = oy - 1 + iy;
        const bool rok = (r >= 0) && (r < 56);
        const int rc   = rok ? r : 0;
        float rb[12];                         // rb[m] = image col 4tx-4+m
        #pragma unroll
        for (int k = 0; k < 3; k++) {
            const int cx  = tx - 1 + k;
            const bool cv = (cx >= 0) && (cx < 14);
            const int cc2 = cv ? cx : 0;
            const bool ok = rok && cv;
            float4 v = *(const float4*)(plane + rc*56 + 4*cc2);  // always in-bounds
            rb[4*k+0] = ok ? v.x : 0.f;
            rb[4*k+1] = ok ? v.y : 0.f;
            rb[4*k+2] = ok ? v.z : 0.f;
            rb[4*k+3] = ok ? v.w : 0.f;
        }
        #pragma unroll
        for (int tyy = 0; tyy < 4; tyy++) {
            const int ky = iy - tyy;          // tap row, needs 0..2
            if (ky >= 0 && ky < 3) {
                #pragma unroll
                for (int e = 0; e < 4; e++)
                    #pragma unroll
                    for (int dj = 0; dj < 3; dj++) {
                        const float xv = rb[3 + e + dj];   // image col 4tx+e+dj-1
                        const f32x2 xv2 = {xv, xv};
                        y12a[tyy][e] = __builtin_elementwise_fma(xv2, w12[ky*3+dj], y12a[tyy][e]);
                    }
            }
        }
    }
    #pragma unroll
    for (int tyy = 0; tyy < 4; tyy++)
        #pragma unroll
        for (int e = 0; e < 4; e++) {
            f32x2 yb = __builtin_elementwise_fma(y12a[tyy][e], sc12, be12);
            float a = fminf(fmaxf(yb.x, 0.f), 6.f);
            res[tyy][e] = a * yb.y;
        }
}

// ---------------- Kernel 1: fuse (no store) -> pooled block means + plane mean ----
// 4096 blocks x 256 threads. pooled stored transposed: [b][p][c], p=49 = plane mean.
__global__ __launch_bounds__(256) void k1_pool(
    const float* __restrict__ x1,
    const float* __restrict__ dw1w, const float* __restrict__ g1, const float* __restrict__ b1,
    const float* __restrict__ m1, const float* __restrict__ v1,
    const float* __restrict__ dw2w, const float* __restrict__ g2, const float* __restrict__ b2,
    const float* __restrict__ m2, const float* __restrict__ v2,
    float* __restrict__ pooled)  // ws: [B][50][C]
{
    const int bc = blockIdx.x;        // b*256 + c
    const int c  = bc & 255;
    const int b  = bc >> 8;
    const int t  = threadIdx.x;

    __shared__ float part[196];

    f32x2 w12[9];
    #pragma unroll
    for (int k = 0; k < 9; k++) w12[k] = (f32x2){dw1w[c*9+k], dw2w[c*9+k]};
    const float sc1 = g1[c] * rsqrtf(v1[c] + 1e-5f);
    const float be1 = b1[c] - m1[c] * sc1;
    const float sc2 = g2[c] * rsqrtf(v2[c] + 1e-5f);
    const float be2 = b2[c] - m2[c] * sc2;
    const f32x2 sc12 = {sc1, sc2};
    const f32x2 be12 = {be1, be2};

    if (t < 196) {
        const int ty = t / 14, tx = t - ty * 14;
        float res[4][4];
        fuse_tile(x1 + (size_t)bc * NPIX, ty, tx, w12, sc12, be12, res);
        float s = 0.f;
        #pragma unroll
        for (int a = 0; a < 4; a++)
            #pragma unroll
            for (int e = 0; e < 4; e++) s += res[a][e];
        part[t] = s;   // tile (ty,tx) lies wholly in pool cell (ty>>1, tx>>1)
    }
    __syncthreads();
    if (t < 64) {
        float cs = 0.f;
        if (t < 49) {
            int ph = t / 7, pw = t - ph * 7;
            cs = part[(2*ph  )*14 + 2*pw] + part[(2*ph  )*14 + 2*pw + 1]
               + part[(2*ph+1)*14 + 2*pw] + part[(2*ph+1)*14 + 2*pw + 1];
            pooled[((size_t)(b * 50 + t)) * 256 + c] = cs * (1.f/64.f);
        }
        // wave-0 reduce of the 49 cell sums -> plane mean at p=49
        #pragma unroll
        for (int off = 32; off > 0; off >>= 1) cs += __shfl_down(cs, off);
        if (t == 0)
            pooled[((size_t)(b * 50 + 49)) * 256 + c] = cs * (1.f/64.f) * (1.f/49.f);
    }
}

// ---------------- Kernel 2a': per (b,p) block: coalesced stage -> proj1 -> GELU ----
// grid = 16*50 = 800 blocks x 256 threads. Branch-free (p=49 row precomputed by k1).
__global__ __launch_bounds__(256) void k2a(
    const float* __restrict__ pooled,  // [B][50][C]
    const float* __restrict__ pw1, const float* __restrict__ pb1,
    float* __restrict__ h)             // [B][50][64]
{
    const int blk = blockIdx.x;
    const int b = blk / 50, p = blk - b * 50;
    const int t = threadIdx.x;

    __shared__ __attribute__((aligned(16))) float xs[272];  // x[c] at c + 4*(c>>6)

    xs[t + 4*(t>>6)] = pooled[((size_t)b * 50 + p) * 256 + t];   // coalesced
    __syncthreads();

    // proj1: 64 outputs, 4 lanes each (len-64 partials), shfl reduce, GELU
    const int o = t >> 2, part = t & 3;
    const float4* w4 = (const float4*)(pw1 + o*256 + part*64);
    const float4* x4 = (const float4*)(xs + part*68);   // LDS broadcast, conflict-free
    float acc = 0.f;
    #pragma unroll
    for (int i = 0; i < 16; i++) {
        float4 w = w4[i];
        float4 x = x4[i];
        acc += w.x*x.x + w.y*x.y + w.z*x.z + w.w*x.w;
    }
    acc += __shfl_xor(acc, 1);
    acc += __shfl_xor(acc, 2);
    if (part == 0) {
        float zv = acc + pb1[o];
        h[((size_t)b * 50 + p) * 64 + o] = 0.5f * zv * (1.f + erff(zv * 0.70710678118654752f));
    }
}

// ---------------- Kernel 2b': proj2 + softmax over G + dynamic w/b ------------
// grid = (16 b, 16 c-chunks) x 256 threads. All operands staged in LDS:
// ht[k][p] (conflict-free x reads), wg[cl][k][g] (float4 broadcast reads).
__global__ __launch_bounds__(256) void k2b(
    const float* __restrict__ h, const float* __restrict__ pw2, const float* __restrict__ pb2,
    const float* __restrict__ weight1, const float* __restrict__ bias1,
    float* __restrict__ w_dyn,   // [B*C][49]  (k3-native layout)
    float* __restrict__ b_dyn)   // [B*C]
{
    const int b   = blockIdx.x;
    const int cch = blockIdx.y;       // 0..15, 16 channels each
    const int t   = threadIdx.x;
    const int c_base = cch * 16;

    __shared__ float ht[64*52];                                   // 13.3 KB [k][p]
    __shared__ __attribute__((aligned(16))) float wg[16*64*4];    // 16 KB [cl][k][g]

    // stage h transposed: global [p][k] -> LDS [k][p]
    const float* hp = h + (size_t)b * 50 * 64;
    for (int idx = t; idx < 800; idx += 256) {
        const int p = idx >> 4, k4 = idx & 15;
        float4 v = ((const float4*)(hp + p * 64))[k4];
        ht[(4*k4+0)*52 + p] = v.x;
        ht[(4*k4+1)*52 + p] = v.y;
        ht[(4*k4+2)*52 + p] = v.z;
        ht[(4*k4+3)*52 + p] = v.w;
    }
    // stage pw2 rows for the 64 outputs {g*256 + c_base + cl} as [cl][k][g]
    for (int idx = t; idx < 1024; idx += 256) {
        const int r = idx >> 4, k4 = idx & 15;    // r = g*16+cl
        const int g = r >> 4, cl = r & 15;
        const int o2 = (g << 8) + c_base + cl;
        float4 v = ((const float4*)(pw2 + (size_t)o2 * 64))[k4];
        wg[((cl*64) + 4*k4+0)*4 + g] = v.x;
        wg[((cl*64) + 4*k4+1)*4 + g] = v.y;
        wg[((cl*64) + 4*k4+2)*4 + g] = v.z;
        wg[((cl*64) + 4*k4+3)*4 + g] = v.w;
    }
    __syncthreads();

    for (int idx = t; idx < 800; idx += 256) {
        const int cl = idx / 50, p = idx - cl * 50;
        const int c  = c_base + cl;
        float s0 = pb2[c], s1 = pb2[256 + c], s2 = pb2[512 + c], s3 = pb2[768 + c];
        const float4* wv = (const float4*)wg + cl * 64;
        #pragma unroll
        for (int k = 0; k < 64; k++) {
            const float x = ht[k*52 + p];      // consecutive lanes -> conflict-free
            const float4 w = wv[k];            // same (cl,k) across lanes -> broadcast
            s0 += x * w.x; s1 += x * w.y; s2 += x * w.z; s3 += x * w.w;
        }
        float mx = fmaxf(fmaxf(s0, s1), fmaxf(s2, s3));
        float e0 = expf(s0-mx), e1 = expf(s1-mx), e2 = expf(s2-mx), e3 = expf(s3-mx);
        float inv = 1.f / (e0+e1+e2+e3);
        e0 *= inv; e1 *= inv; e2 *= inv; e3 *= inv;
        if (p < 49) {
            float wvv = e0*weight1[(0*256+c)*49+p] + e1*weight1[(1*256+c)*49+p]
                      + e2*weight1[(2*256+c)*49+p] + e3*weight1[(3*256+c)*49+p];
            w_dyn[((size_t)b*256 + c)*49 + p] = wvv;   // coalesced along p
        } else {
            b_dyn[b*256 + c] = e0*bias1[c] + e1*bias1[256+c] + e2*bias1[512+c] + e3*bias1[768+c];
        }
    }
}

// ---------------- Kernel 3: fuse into LDS halo, then dynamic 7x7 conv ----
// Single barrier: border-zeroing (208 float4, one per thread, disjoint from
// interior) runs concurrently with phase-A fuse writes; then one sync; phase B.
#define S3 68
__global__ __launch_bounds__(256) void k3_dyn(
    const float* __restrict__ x1,
    const float* __restrict__ dw1w, const float* __restrict__ g1, const float* __restrict__ b1,
    const float* __restrict__ m1, const float* __restrict__ v1,
    const float* __restrict__ dw2w, const float* __restrict__ g2, const float* __restrict__ b2,
    const float* __restrict__ m2, const float* __restrict__ v2,
    const float* __restrict__ w_dyn, const float* __restrict__ b_dyn,
    float* __restrict__ out)
{
    const int bc = blockIdx.x;
    const int c  = bc & 255;
    const int t  = threadIdx.x;
    __shared__ __attribute__((aligned(16))) float halo[62*S3];  // 16.9 KB

    // block-uniform constants (scalar path)
    f32x2 w12[9];
    #pragma unroll
    for (int k = 0; k < 9; k++) w12[k] = (f32x2){dw1w[c*9+k], dw2w[c*9+k]};
    const float sc1 = g1[c] * rsqrtf(v1[c] + 1e-5f);
    const float be1 = b1[c] - m1[c] * sc1;
    const float sc2 = g2[c] * rsqrtf(v2[c] + 1e-5f);
    const float be2 = b2[c] - m2[c] * sc2;
    const f32x2 sc12 = {sc1, sc2};
    const f32x2 be12 = {be1, be2};
    float wk[49];
    const float* wp = w_dyn + (size_t)bc * 49;   // block-uniform -> s_loads
    #pragma unroll
    for (int k = 0; k < 49; k++) wk[k] = wp[k];
    const float bias = b_dyn[bc];

    // border zeroing: exactly one float4 per thread (t<208). Regions:
    // rows 0..2 cols 0..63 (48), rows 59..61 cols 0..63 (48),
    // rows 3..58 col-block 0 (56), rows 3..58 col-block 15 (56).
    // Cols 64..67 are never read by phase B (max LDS col = 63).
    if (t < 208) {
        int row, c4;
        if (t < 48)       { row = t >> 4;             c4 = t & 15; }
        else if (t < 96)  { row = 59 + ((t-48) >> 4); c4 = (t-48) & 15; }
        else if (t < 152) { row = 3 + (t - 96);       c4 = 0; }
        else              { row = 3 + (t - 152);      c4 = 15; }
        *(float4*)&halo[row*S3 + 4*c4] = make_float4(0.f, 0.f, 0.f, 0.f);
    }

    const int ty = t / 14, tx = t - ty * 14;
    if (t < 196) {
        float res[4][4];
        fuse_tile(x1 + (size_t)bc * NPIX, ty, tx, w12, sc12, be12, res);
        #pragma unroll
        for (int tyy = 0; tyy < 4; tyy++) {
            float4 r4; r4.x=res[tyy][0]; r4.y=res[tyy][1]; r4.z=res[tyy][2]; r4.w=res[tyy][3];
            *(float4*)&halo[(4*ty + tyy + 3)*S3 + 4 + 4*tx] = r4;
        }
    }
    __syncthreads();

    if (t < 196) {
        const int oy = ty * 4, ox = tx * 4;
        float acc[4][4];
        #pragma unroll
        for (int a = 0; a < 4; a++)
            #pragma unroll
            for (int bb = 0; bb < 4; bb++) acc[a][bb] = bias;

        #pragma unroll
        for (int iy = 0; iy < 10; iy++) {
            const float* hr = &halo[(oy+iy)*S3 + ox];  // aligned
            float4 a = *(const float4*)hr;             // 3x ds_read_b128
            float4 b = *(const float4*)(hr + 4);
            float4 cc = *(const float4*)(hr + 8);
            float row[12];                             // row[m] = image col ox+m-4
            row[0]=a.x; row[1]=a.y; row[2]=a.z; row[3]=a.w;
            row[4]=b.x; row[5]=b.y; row[6]=b.z; row[7]=b.w;
            row[8]=cc.x; row[9]=cc.y; row[10]=cc.z; row[11]=cc.w;
            #pragma unroll
            for (int tyy = 0; tyy < 4; tyy++) {
                const int ky = iy - tyy;
                if (ky >= 0 && ky < 7) {
                    #pragma unroll
                    for (int txx = 0; txx < 4; txx++)
                        #pragma unroll
                        for (int kx = 0; kx < 7; kx++)
                            acc[tyy][txx] += row[1+txx+kx] * wk[ky*7+kx];
                }
            }
        }
        float* op = out + (size_t)bc * NPIX;
        #pragma unroll
        for (int tyy = 0; tyy < 4; tyy++) {
            float4 r4; r4.x = acc[tyy][0]; r4.y = acc[tyy][1]; r4.z = acc[tyy][2]; r4.w = acc[tyy][3];
            *(float4*)(op + (oy+tyy)*56 + ox) = r4;
        }
    }
}

extern "C" void kernel_launch(void* const* d_in, const int* in_sizes, int n_in,
                              void* d_out, int out_size, void* d_ws, size_t ws_size,
                              hipStream_t stream) {
    const float* x1    = (const float*)d_in[0];
    const float* dw1w  = (const float*)d_in[1];
    const float* dw1g  = (const float*)d_in[2];
    const float* dw1b  = (const float*)d_in[3];
    const float* dw1m  = (const float*)d_in[4];
    const float* dw1v  = (const float*)d_in[5];
    const float* dw2w  = (const float*)d_in[6];
    const float* dw2g  = (const float*)d_in[7];
    const float* dw2b  = (const float*)d_in[8];
    const float* dw2m  = (const float*)d_in[9];
    const float* dw2v  = (const float*)d_in[10];
    const float* weight1 = (const float*)d_in[11];
    const float* bias1   = (const float*)d_in[12];
    const float* pw1     = (const float*)d_in[13];
    const float* pb1     = (const float*)d_in[14];
    const float* pw2     = (const float*)d_in[15];
    const float* pb2     = (const float*)d_in[16];

    float* out = (float*)d_out;
    float* ws  = (float*)d_ws;
    float* pooled = ws;                    // 16*50*256 = 204,800
    float* h      = ws + 204800;           // 16*50*64  =  51,200
    float* w_dyn  = ws + 256000;           // 16*256*49 = 200,704
    float* b_dyn  = ws + 456704;           // 16*256    =   4,096
    // total ws: 460,800 floats = 1.84 MB (keep small: harness resets d_ws per iter)

    k1_pool<<<BATCH*CH, 256, 0, stream>>>(x1, dw1w, dw1g, dw1b, dw1m, dw1v,
                                          dw2w, dw2g, dw2b, dw2m, dw2v, pooled);
    k2a<<<800, 256, 0, stream>>>(pooled, pw1, pb1, h);
    k2b<<<dim3(BATCH, 16), 256, 0, stream>>>(h, pw2, pb2, weight1, bias1, w_dyn, b_dyn);
    k3_dyn<<<BATCH*CH, 256, 0, stream>>>(x1, dw1w, dw1g, dw1b, dw1m, dw1v,
                                         dw2w, dw2g, dw2b, dw2m, dw2v,
                                         w_dyn, b_dyn, out);
}

// Round 5
// 182.757 us; speedup vs baseline: 1.0517x; 1.0517x over previous
//
#include <hip/hip_runtime.h>
#include <math.h>

#define BATCH 16
#define CH 256
#define HW 56
#define NPIX (HW*HW)          // 3136

typedef float f32x2 __attribute__((ext_vector_type(2)));

// ---- shared device helper: compute 4x4 tile of x_fuse = relu6(bn1(dw1(x))) * bn2(dw2(x))
// Dual 3x3 convs packed as f32x2 (v_pk_fma_f32 path); scalarizes harmlessly if unsupported.
// Tile at rows 4ty..4ty+3, cols 4tx..4tx+3 (ty,tx in 0..13).
__device__ __forceinline__ void fuse_tile(
    const float* __restrict__ plane, int ty, int tx,
    const f32x2 w12[9], f32x2 sc12, f32x2 be12,
    float res[4][4])
{
    const int oy = 4 * ty;
    f32x2 y12a[4][4];
    #pragma unroll
    for (int a = 0; a < 4; a++)
        #pragma unroll
        for (int e = 0; e < 4; e++) y12a[a][e] = (f32x2){0.f, 0.f};

    #pragma unroll
    for (int iy = 0; iy < 6; iy++) {         // input rows oy-1 .. oy+4
        const int r    = oy - 1 + iy;
        const bool rok = (r >= 0) && (r < 56);
        const int rc   = rok ? r : 0;
        float rb[12];                         // rb[m] = image col 4tx-4+m
        #pragma unroll
        for (int k = 0; k < 3; k++) {
            const int cx  = tx - 1 + k;
            const bool cv = (cx >= 0) && (cx < 14);
            const int cc2 = cv ? cx : 0;
            const bool ok = rok && cv;
            float4 v = *(const float4*)(plane + rc*56 + 4*cc2);  // always in-bounds
            rb[4*k+0] = ok ? v.x : 0.f;
            rb[4*k+1] = ok ? v.y : 0.f;
            rb[4*k+2] = ok ? v.z : 0.f;
            rb[4*k+3] = ok ? v.w : 0.f;
        }
        #pragma unroll
        for (int tyy = 0; tyy < 4; tyy++) {
            const int ky = iy - tyy;          // tap row, needs 0..2
            if (ky >= 0 && ky < 3) {
                #pragma unroll
                for (int e = 0; e < 4; e++)
                    #pragma unroll
                    for (int dj = 0; dj < 3; dj++) {
                        const float xv = rb[3 + e + dj];   // image col 4tx+e+dj-1
                        const f32x2 xv2 = {xv, xv};
                        y12a[tyy][e] = __builtin_elementwise_fma(xv2, w12[ky*3+dj], y12a[tyy][e]);
                    }
            }
        }
    }
    #pragma unroll
    for (int tyy = 0; tyy < 4; tyy++)
        #pragma unroll
        for (int e = 0; e < 4; e++) {
            f32x2 yb = __builtin_elementwise_fma(y12a[tyy][e], sc12, be12);
            float a = fminf(fmaxf(yb.x, 0.f), 6.f);
            res[tyy][e] = a * yb.y;
        }
}

// ---------------- Kernel 1: fuse (no store) -> pooled block means + plane mean ----
// 4096 blocks x 256 threads. pooled stored transposed: [b][p][c], p=49 = plane mean.
__global__ __launch_bounds__(256) void k1_pool(
    const float* __restrict__ x1,
    const float* __restrict__ dw1w, const float* __restrict__ g1, const float* __restrict__ b1,
    const float* __restrict__ m1, const float* __restrict__ v1,
    const float* __restrict__ dw2w, const float* __restrict__ g2, const float* __restrict__ b2,
    const float* __restrict__ m2, const float* __restrict__ v2,
    float* __restrict__ pooled)  // ws: [B][50][C]
{
    const int bc = blockIdx.x;        // b*256 + c
    const int c  = bc & 255;
    const int b  = bc >> 8;
    const int t  = threadIdx.x;

    __shared__ float part[196];

    f32x2 w12[9];
    #pragma unroll
    for (int k = 0; k < 9; k++) w12[k] = (f32x2){dw1w[c*9+k], dw2w[c*9+k]};
    const float sc1 = g1[c] * rsqrtf(v1[c] + 1e-5f);
    const float be1 = b1[c] - m1[c] * sc1;
    const float sc2 = g2[c] * rsqrtf(v2[c] + 1e-5f);
    const float be2 = b2[c] - m2[c] * sc2;
    const f32x2 sc12 = {sc1, sc2};
    const f32x2 be12 = {be1, be2};

    if (t < 196) {
        const int ty = t / 14, tx = t - ty * 14;
        float res[4][4];
        fuse_tile(x1 + (size_t)bc * NPIX, ty, tx, w12, sc12, be12, res);
        float s = 0.f;
        #pragma unroll
        for (int a = 0; a < 4; a++)
            #pragma unroll
            for (int e = 0; e < 4; e++) s += res[a][e];
        part[t] = s;   // tile (ty,tx) lies wholly in pool cell (ty>>1, tx>>1)
    }
    __syncthreads();
    if (t < 64) {
        float cs = 0.f;
        if (t < 49) {
            int ph = t / 7, pw = t - ph * 7;
            cs = part[(2*ph  )*14 + 2*pw] + part[(2*ph  )*14 + 2*pw + 1]
               + part[(2*ph+1)*14 + 2*pw] + part[(2*ph+1)*14 + 2*pw + 1];
            pooled[((size_t)(b * 50 + t)) * 256 + c] = cs * (1.f/64.f);
        }
        // wave-0 reduce of the 49 cell sums -> plane mean at p=49
        #pragma unroll
        for (int off = 32; off > 0; off >>= 1) cs += __shfl_down(cs, off);
        if (t == 0)
            pooled[((size_t)(b * 50 + 49)) * 256 + c] = cs * (1.f/64.f) * (1.f/49.f);
    }
}

// ---------------- Kernel 2a': per (b,p) block: coalesced stage -> proj1 -> GELU ----
// grid = 16*50 = 800 blocks x 256 threads. Branch-free (p=49 row precomputed by k1).
__global__ __launch_bounds__(256) void k2a(
    const float* __restrict__ pooled,  // [B][50][C]
    const float* __restrict__ pw1, const float* __restrict__ pb1,
    float* __restrict__ h)             // [B][50][64]
{
    const int blk = blockIdx.x;
    const int b = blk / 50, p = blk - b * 50;
    const int t = threadIdx.x;

    __shared__ __attribute__((aligned(16))) float xs[272];  // x[c] at c + 4*(c>>6)

    xs[t + 4*(t>>6)] = pooled[((size_t)b * 50 + p) * 256 + t];   // coalesced
    __syncthreads();

    // proj1: 64 outputs, 4 lanes each (len-64 partials), shfl reduce, GELU
    const int o = t >> 2, part = t & 3;
    const float4* w4 = (const float4*)(pw1 + o*256 + part*64);
    const float4* x4 = (const float4*)(xs + part*68);   // LDS broadcast, conflict-free
    float acc = 0.f;
    #pragma unroll
    for (int i = 0; i < 16; i++) {
        float4 w = w4[i];
        float4 x = x4[i];
        acc += w.x*x.x + w.y*x.y + w.z*x.z + w.w*x.w;
    }
    acc += __shfl_xor(acc, 1);
    acc += __shfl_xor(acc, 2);
    if (part == 0) {
        float zv = acc + pb1[o];
        h[((size_t)b * 50 + p) * 64 + o] = 0.5f * zv * (1.f + erff(zv * 0.70710678118654752f));
    }
}

// ---------------- Kernel 2b': proj2 + softmax over G + dynamic w/b ------------
// grid = (16 b, 16 c-chunks) x 256 threads. All operands staged in LDS:
// ht[k][p] (conflict-free x reads), wg[cl][k][g] (float4 broadcast reads).
__global__ __launch_bounds__(256) void k2b(
    const float* __restrict__ h, const float* __restrict__ pw2, const float* __restrict__ pb2,
    const float* __restrict__ weight1, const float* __restrict__ bias1,
    float* __restrict__ w_dyn,   // [B*C][49]  (k3-native layout)
    float* __restrict__ b_dyn)   // [B*C]
{
    const int b   = blockIdx.x;
    const int cch = blockIdx.y;       // 0..15, 16 channels each
    const int t   = threadIdx.x;
    const int c_base = cch * 16;

    __shared__ float ht[64*52];                                   // 13.3 KB [k][p]
    __shared__ __attribute__((aligned(16))) float wg[16*64*4];    // 16 KB [cl][k][g]

    // stage h transposed: global [p][k] -> LDS [k][p]
    const float* hp = h + (size_t)b * 50 * 64;
    for (int idx = t; idx < 800; idx += 256) {
        const int p = idx >> 4, k4 = idx & 15;
        float4 v = ((const float4*)(hp + p * 64))[k4];
        ht[(4*k4+0)*52 + p] = v.x;
        ht[(4*k4+1)*52 + p] = v.y;
        ht[(4*k4+2)*52 + p] = v.z;
        ht[(4*k4+3)*52 + p] = v.w;
    }
    // stage pw2 rows for the 64 outputs {g*256 + c_base + cl} as [cl][k][g]
    for (int idx = t; idx < 1024; idx += 256) {
        const int r = idx >> 4, k4 = idx & 15;    // r = g*16+cl
        const int g = r >> 4, cl = r & 15;
        const int o2 = (g << 8) + c_base + cl;
        float4 v = ((const float4*)(pw2 + (size_t)o2 * 64))[k4];
        wg[((cl*64) + 4*k4+0)*4 + g] = v.x;
        wg[((cl*64) + 4*k4+1)*4 + g] = v.y;
        wg[((cl*64) + 4*k4+2)*4 + g] = v.z;
        wg[((cl*64) + 4*k4+3)*4 + g] = v.w;
    }
    __syncthreads();

    for (int idx = t; idx < 800; idx += 256) {
        const int cl = idx / 50, p = idx - cl * 50;
        const int c  = c_base + cl;
        float s0 = pb2[c], s1 = pb2[256 + c], s2 = pb2[512 + c], s3 = pb2[768 + c];
        const float4* wv = (const float4*)wg + cl * 64;
        #pragma unroll
        for (int k = 0; k < 64; k++) {
            const float x = ht[k*52 + p];      // consecutive lanes -> conflict-free
            const float4 w = wv[k];            // same (cl,k) across lanes -> broadcast
            s0 += x * w.x; s1 += x * w.y; s2 += x * w.z; s3 += x * w.w;
        }
        float mx = fmaxf(fmaxf(s0, s1), fmaxf(s2, s3));
        float e0 = expf(s0-mx), e1 = expf(s1-mx), e2 = expf(s2-mx), e3 = expf(s3-mx);
        float inv = 1.f / (e0+e1+e2+e3);
        e0 *= inv; e1 *= inv; e2 *= inv; e3 *= inv;
        if (p < 49) {
            float wvv = e0*weight1[(0*256+c)*49+p] + e1*weight1[(1*256+c)*49+p]
                      + e2*weight1[(2*256+c)*49+p] + e3*weight1[(3*256+c)*49+p];
            w_dyn[((size_t)b*256 + c)*49 + p] = wvv;   // coalesced along p
        } else {
            b_dyn[b*256 + c] = e0*bias1[c] + e1*bias1[256+c] + e2*bias1[512+c] + e3*bias1[768+c];
        }
    }
}

// ---------------- Kernel 3: fuse into LDS halo, then dynamic 7x7 conv ----
// LDS layout: 62 rows x 64 floats, XOR-swizzled at float4-chunk granularity:
//   physical float index = row*64 + 4*(chunk ^ ((row>>2)&7)) + (col&3)
// Rationale: with plain stride (68 or 64), wave lanes at the same iy span tile-rows
// 4 apart whose bank offsets collide -> 6-way ds_read_b128 conflicts (1.23e7/dispatch).
// The (row>>2) XOR gives consecutive ty distinct mod-8 bank classes; only the free
// tx/tx+8 2-way aliasing remains. All accesses stay 16B-aligned chunks.
#define SWZ(row, chunk) ((row)*64 + 4*((chunk) ^ (((row)>>2)&7)))
__global__ __launch_bounds__(256) void k3_dyn(
    const float* __restrict__ x1,
    const float* __restrict__ dw1w, const float* __restrict__ g1, const float* __restrict__ b1,
    const float* __restrict__ m1, const float* __restrict__ v1,
    const float* __restrict__ dw2w, const float* __restrict__ g2, const float* __restrict__ b2,
    const float* __restrict__ m2, const float* __restrict__ v2,
    const float* __restrict__ w_dyn, const float* __restrict__ b_dyn,
    float* __restrict__ out)
{
    const int bc = blockIdx.x;
    const int c  = bc & 255;
    const int t  = threadIdx.x;
    __shared__ __attribute__((aligned(16))) float halo[62*64];  // 15.5 KB

    // block-uniform constants (scalar path)
    f32x2 w12[9];
    #pragma unroll
    for (int k = 0; k < 9; k++) w12[k] = (f32x2){dw1w[c*9+k], dw2w[c*9+k]};
    const float sc1 = g1[c] * rsqrtf(v1[c] + 1e-5f);
    const float be1 = b1[c] - m1[c] * sc1;
    const float sc2 = g2[c] * rsqrtf(v2[c] + 1e-5f);
    const float be2 = b2[c] - m2[c] * sc2;
    const f32x2 sc12 = {sc1, sc2};
    const f32x2 be12 = {be1, be2};
    float wk[49];
    const float* wp = w_dyn + (size_t)bc * 49;   // block-uniform -> s_loads
    #pragma unroll
    for (int k = 0; k < 49; k++) wk[k] = wp[k];
    const float bias = b_dyn[bc];

    // border zeroing: exactly one float4-chunk per thread (t<208). Regions:
    // rows 0..2 all 16 chunks (48), rows 59..61 all 16 chunks (48),
    // rows 3..58 chunk 0 (56), rows 3..58 chunk 15 (56). Disjoint from interior.
    // LDS row r = image row r-3; chunk 0 = image cols -4..-1, chunk 15 = 56..59.
    if (t < 208) {
        int row, c4;
        if (t < 48)       { row = t >> 4;             c4 = t & 15; }
        else if (t < 96)  { row = 59 + ((t-48) >> 4); c4 = (t-48) & 15; }
        else if (t < 152) { row = 3 + (t - 96);       c4 = 0; }
        else              { row = 3 + (t - 152);      c4 = 15; }
        *(float4*)&halo[SWZ(row, c4)] = make_float4(0.f, 0.f, 0.f, 0.f);
    }

    const int ty = t / 14, tx = t - ty * 14;
    if (t < 196) {
        float res[4][4];
        fuse_tile(x1 + (size_t)bc * NPIX, ty, tx, w12, sc12, be12, res);
        #pragma unroll
        for (int tyy = 0; tyy < 4; tyy++) {
            float4 r4; r4.x=res[tyy][0]; r4.y=res[tyy][1]; r4.z=res[tyy][2]; r4.w=res[tyy][3];
            // image row 4ty+tyy -> LDS row +3; image col 4tx -> LDS col 4+4tx = chunk tx+1
            *(float4*)&halo[SWZ(4*ty + tyy + 3, tx + 1)] = r4;
        }
    }
    __syncthreads();

    if (t < 196) {
        const int oy = ty * 4, ox = tx * 4;
        float acc[4][4];
        #pragma unroll
        for (int a = 0; a < 4; a++)
            #pragma unroll
            for (int bb = 0; bb < 4; bb++) acc[a][bb] = bias;

        #pragma unroll
        for (int iy = 0; iy < 10; iy++) {
            const int row = oy + iy;                   // LDS row
            float4 a  = *(const float4*)&halo[SWZ(row, tx    )];
            float4 b  = *(const float4*)&halo[SWZ(row, tx + 1)];
            float4 cc = *(const float4*)&halo[SWZ(row, tx + 2)];
            float rowv[12];                            // rowv[m] = image col ox+m-4
            rowv[0]=a.x; rowv[1]=a.y; rowv[2]=a.z; rowv[3]=a.w;
            rowv[4]=b.x; rowv[5]=b.y; rowv[6]=b.z; rowv[7]=b.w;
            rowv[8]=cc.x; rowv[9]=cc.y; rowv[10]=cc.z; rowv[11]=cc.w;
            #pragma unroll
            for (int tyy = 0; tyy < 4; tyy++) {
                const int ky = iy - tyy;
                if (ky >= 0 && ky < 7) {
                    #pragma unroll
                    for (int txx = 0; txx < 4; txx++)
                        #pragma unroll
                        for (int kx = 0; kx < 7; kx++)
                            acc[tyy][txx] += rowv[1+txx+kx] * wk[ky*7+kx];
                }
            }
        }
        float* op = out + (size_t)bc * NPIX;
        #pragma unroll
        for (int tyy = 0; tyy < 4; tyy++) {
            float4 r4; r4.x = acc[tyy][0]; r4.y = acc[tyy][1]; r4.z = acc[tyy][2]; r4.w = acc[tyy][3];
            *(float4*)(op + (oy+tyy)*56 + ox) = r4;
        }
    }
}

extern "C" void kernel_launch(void* const* d_in, const int* in_sizes, int n_in,
                              void* d_out, int out_size, void* d_ws, size_t ws_size,
                              hipStream_t stream) {
    const float* x1    = (const float*)d_in[0];
    const float* dw1w  = (const float*)d_in[1];
    const float* dw1g  = (const float*)d_in[2];
    const float* dw1b  = (const float*)d_in[3];
    const float* dw1m  = (const float*)d_in[4];
    const float* dw1v  = (const float*)d_in[5];
    const float* dw2w  = (const float*)d_in[6];
    const float* dw2g  = (const float*)d_in[7];
    const float* dw2b  = (const float*)d_in[8];
    const float* dw2m  = (const float*)d_in[9];
    const float* dw2v  = (const float*)d_in[10];
    const float* weight1 = (const float*)d_in[11];
    const float* bias1   = (const float*)d_in[12];
    const float* pw1     = (const float*)d_in[13];
    const float* pb1     = (const float*)d_in[14];
    const float* pw2     = (const float*)d_in[15];
    const float* pb2     = (const float*)d_in[16];

    float* out = (float*)d_out;
    float* ws  = (float*)d_ws;
    float* pooled = ws;                    // 16*50*256 = 204,800
    float* h      = ws + 204800;           // 16*50*64  =  51,200
    float* w_dyn  = ws + 256000;           // 16*256*49 = 200,704
    float* b_dyn  = ws + 456704;           // 16*256    =   4,096
    // total ws: 460,800 floats = 1.84 MB (keep small: harness resets d_ws per iter)

    k1_pool<<<BATCH*CH, 256, 0, stream>>>(x1, dw1w, dw1g, dw1b, dw1m, dw1v,
                                          dw2w, dw2g, dw2b, dw2m, dw2v, pooled);
    k2a<<<800, 256, 0, stream>>>(pooled, pw1, pb1, h);
    k2b<<<dim3(BATCH, 16), 256, 0, stream>>>(h, pw2, pb2, weight1, bias1, w_dyn, b_dyn);
    k3_dyn<<<BATCH*CH, 256, 0, stream>>>(x1, dw1w, dw1g, dw1b, dw1m, dw1v,
                                         dw2w, dw2g, dw2b, dw2m, dw2v,
                                         w_dyn, b_dyn, out);
}